// Round 1
// 289.498 us; speedup vs baseline: 1.1082x; 1.1082x over previous
//
#include <hip/hip_runtime.h>
#include <cmath>

// PhaseAwareClassifier on MI355X — R18: register-cached conn A-frags + exact-
// zero step truncation.
// R17 post-mortem: step = [GEMM phase: max(MFMA issue 7.0k cyc, LDS reads
// 7.9k cyc)] + [epilogue ~4-6k cyc], barrier-serialized (MfmaUtil 34%,
// VALUBusy 62%). Fixes here:
//  1) conn is time-invariant: each wave caches its 12 A-frags for k-chunks
//     0..7 (kt=0,1) in 48 VGPRs once; per-step LDS reads 600->456 per CU ->
//     GEMM phase becomes MFMA-issue-bound.
//  2) t=1: out(0) rows >=49 are exactly zero (injection only) -> kt 0,1
//     suffice (and those are register-resident). t=9: only rows 121..130 are
//     consumed -> mg 0/1 waves idle, mg2 skips tile 6 + OB writeback.
//  3) OB zero-init removed: t=0 epilogue writes every OB cell before any read.
// All changes are bit-exact vs R17 (same accumulation order; skipped terms
// exactly zero). Discipline kept: unroll(1) on LDS kt-loop (R15), constant
// bounds (R11), no forced reg caps (R2/R6). LDS total 156,672 B unchanged.

#define NSTEPS  10
#define INJ_ST  4
#define MT      144          // padded M (9 tiles of 16)

typedef __bf16 bf16x8 __attribute__((ext_vector_type(8)));
typedef __bf16 bf16x4 __attribute__((ext_vector_type(4)));
typedef short  short8 __attribute__((ext_vector_type(8)));
typedef float  f32x4  __attribute__((ext_vector_type(4)));

// workspace layout (float offsets)
#define WS_MAX    0          // 1      enc_max (uint-ordered float)
#define WS_ENERGY 64         // 1280   energy[b][10]
#define WS_GSP    2048       // 144    gsp2[j] = -2*log2(e)*softplus(gain)
#define WS_CONN   4096       // 2 bf16 mats [20][144][8] chunked: Cr, Ci
#define WS_INJ    32768      // 100352 inj[b][49][16] = px * 1.02/enc_max

__global__ void k_init(float* ws) {
    int i = blockIdx.x * 256 + threadIdx.x;
    if (i == 0) ws[WS_MAX] = 0.f;
    if (i < 1280) ws[WS_ENERGY + i] = 0.f;
}

__global__ void k_max(const float* __restrict__ img, float* ws, int n) {
    __shared__ float sm[256];
    float v = 0.f;
    for (int i = blockIdx.x * blockDim.x + threadIdx.x; i < n; i += gridDim.x * blockDim.x)
        v = fmaxf(v, fabsf(img[i]));
    sm[threadIdx.x] = v;
    __syncthreads();
    for (int s = 128; s > 0; s >>= 1) {
        if (threadIdx.x < s) sm[threadIdx.x] = fmaxf(sm[threadIdx.x], sm[threadIdx.x + s]);
        __syncthreads();
    }
    if (threadIdx.x == 0)
        atomicMax((unsigned int*)(ws + WS_MAX), __float_as_uint(sm[0]));
}

__global__ void k_prep(const float* __restrict__ img,
                       const float* __restrict__ cr, const float* __restrict__ ci,
                       const float* __restrict__ phase, const float* __restrict__ gain,
                       float* ws) {
    int i = blockIdx.x * 256 + threadIdx.x;
    __bf16* Cb = (__bf16*)(ws + WS_CONN);
    const int NCE = MT * 160;              // 23040 (m,k) pairs
    if (i < NCE) {
        int m = i / 160, k = i % 160;
        float vr = 0.f, vi = 0.f;
        if (m < 131 && k < 131) {
            float a = cr[k * 131 + m], b = ci[k * 131 + m];
            float ph = phase[m];
            float cp = cosf(ph), sp = sinf(ph);
            vr = a * cp - b * sp;
            vi = a * sp + b * cp;
        }
        int ca = ((k >> 3) * MT + m) * 8 + (k & 7);    // chunked addr
        Cb[ca]       = (__bf16)vr;
        Cb[NCE + ca] = (__bf16)vi;
    } else if (i < NCE + MT) {
        int j = i - NCE;
        float g = 0.f;
        if (j < 131) {
            float x = gain[j];
            g = (x > 20.f) ? x : log1pf(expf(x));  // softplus
        }
        ws[WS_GSP + j] = g * -2.8853901817f;        // -2*log2(e)*g
    } else if (i < NCE + MT + 128 * 49 * 16) {
        int q = i - NCE - MT;
        int m = q & 15, jj = (q >> 4) % 49, b = q / (49 * 16);
        int u = m >> 2, v2 = m & 3, pi = jj / 7, pj = jj % 7;
        float px = img[b * 784 + (pi * 4 + u) * 28 + (pj * 4 + v2)];
        float mx = ws[WS_MAX];
        float sc = (mx > 1e-8f) ? (1.02f / mx) : 1.02f;   // 0.85*4*0.3
        ws[WS_INJ + q] = px * sc;
    }
}

static __device__ __forceinline__ f32x4 MF(bf16x8 a, bf16x8 b, f32x4 c) {
    return __builtin_amdgcn_mfma_f32_16x16x32_bf16(a, b, c, 0, 0, 0);
}
static __device__ __forceinline__ bf16x8 bneg(bf16x8 a) {
    short8 t = __builtin_bit_cast(short8, a) ^ (short8)(short)0x8000;
    return __builtin_bit_cast(bf16x8, t);
}

// 3-Mtile complex MFMA group (12 MFMAs); order identical to R17.
#define CMUL3(AR0, AI0, AR1, AI1, AR2, AI2, BR, BI, BNI, P)            \
    accr[P]     = MF(AR0, BR,  accr[P]);                               \
    accr[P]     = MF(AI0, BNI, accr[P]);                               \
    acci[P]     = MF(AR0, BI,  acci[P]);                               \
    acci[P]     = MF(AI0, BR,  acci[P]);                               \
    accr[2 + P] = MF(AR1, BR,  accr[2 + P]);                           \
    accr[2 + P] = MF(AI1, BNI, accr[2 + P]);                           \
    acci[2 + P] = MF(AR1, BI,  acci[2 + P]);                           \
    acci[2 + P] = MF(AI1, BR,  acci[2 + P]);                           \
    accr[4 + P] = MF(AR2, BR,  accr[4 + P]);                           \
    accr[4 + P] = MF(AI2, BNI, accr[4 + P]);                           \
    acci[4 + P] = MF(AR2, BI,  acci[4 + P]);                           \
    acci[4 + P] = MF(AI2, BR,  acci[4 + P]);

// 2-Mtile variant (tiles 7,8 only) for the truncated last step.
#define CMUL2(AR1, AI1, AR2, AI2, BR, BI, BNI, P)                      \
    accr[2 + P] = MF(AR1, BR,  accr[2 + P]);                           \
    accr[2 + P] = MF(AI1, BNI, accr[2 + P]);                           \
    acci[2 + P] = MF(AR1, BI,  acci[2 + P]);                           \
    acci[2 + P] = MF(AI1, BR,  acci[2 + P]);                           \
    accr[4 + P] = MF(AR2, BR,  accr[4 + P]);                           \
    accr[4 + P] = MF(AI2, BNI, accr[4 + P]);                           \
    acci[4 + P] = MF(AR2, BI,  acci[4 + P]);                           \
    acci[4 + P] = MF(AI2, BR,  acci[4 + P]);

__global__ __launch_bounds__(768, 1)
void k_main(const float* __restrict__ ws, float* __restrict__ energy) {
    __shared__ __bf16 OB[2][18 * 128 * 8];         // 73,728 B: Or, Oi (18 ch)
    __shared__ __bf16 CrL[18 * MT * 8];            // 41,472 B: Cr (18 ch)
    __shared__ __bf16 CiL[18 * MT * 8];            // 41,472 B: Ci (18 ch)
    // total 156,672 B -> 1 block/CU. scrE aliases CrL ch0-1 (never LDS-read
    // after the kt0/1 register cache is loaded).
    const int tid  = threadIdx.x;
    const int lane = tid & 63;
    const int ln15 = lane & 15;
    const int quad = lane >> 4;
    const int wv   = __builtin_amdgcn_readfirstlane(tid >> 6);  // 0..11
    const int mg   = wv >> 2;                       // 0..2: M-tiles 3mg..3mg+2
    const int ng   = wv & 3;                        // N-tiles 2ng, 2ng+1
    const int b    = blockIdx.x >> 3;               // 8 blocks per image
    const int m    = ln15;

    const float* __restrict__ gsp2 = ws + WS_GSP;
    const float* __restrict__ injb = ws + WS_INJ;

    __bf16* __restrict__ OBr = &OB[0][0];
    __bf16* __restrict__ OBi = &OB[1][0];
    float* scrE = (float*)CrL;                      // alias: ch0-1, end only

    // per-position encoding weight (pn = 0,1)
    float wls[2];
#pragma unroll
    for (int q = 0; q < 2; ++q) {
        int l = ((blockIdx.x & 7) * 8 + 2 * ng + q) & 63;
        wls[q] = 1.0f - fabsf((float)l - 32.0f) * (1.0f / 64.0f);
    }

    // stage Cr, Ci (chunks 0..17) -> LDS. OB zero-init removed: t=0 epilogue
    // writes every OB cell (all 18 chunks x 128 cols) before the first read.
    {
        const int4* srcR = (const int4*)(ws + WS_CONN);
        const int4* srcI = (const int4*)(ws + WS_CONN + (MT * 160 / 2)); // +20ch
        int4* dstR = (int4*)CrL;
        int4* dstI = (int4*)CiL;
        for (int i = tid; i < 2592; i += 768) { dstR[i] = srcR[i]; dstI[i] = srcI[i]; }
    }

    f32x4 accr[6], acci[6];                         // acc == 4*field; p=pm*2+pn
#pragma unroll
    for (int p = 0; p < 6; ++p) { accr[p] = (f32x4)0.f; acci[p] = (f32x4)0.f; }

    // injection (rows j<49 -> mg 0 fully, mg 1 only j=48; constant indices)
    auto inj_add = [&]() {
        if (mg < 2) {
#pragma unroll
            for (int p = 0; p < 6; ++p) {
                const int j0 = (3 * mg + (p >> 1)) * 16 + quad * 4;
#pragma unroll
                for (int r = 0; r < 4; ++r) {
                    int j = j0 + r;
                    if (j < 49) accr[p][r] += injb[(b * 49 + j) * 16 + m] * wls[p & 1];
                }
            }
        }
    };

    // epilogue: out = tanh-rescale(0.25*acc) -> bf16 chunked LDS write
    auto epilogue = [&]() {
#pragma unroll
        for (int p = 0; p < 6; ++p) {
            const int j0 = (3 * mg + (p >> 1)) * 16 + quad * 4;
            const int n  = (2 * ng + (p & 1)) * 16 + ln15;
            float g2[4];
            *(float4*)g2 = *(const float4*)(gsp2 + j0);
            bf16x4 pr, pi;
#pragma unroll
            for (int r = 0; r < 4; ++r) {
                float fr = accr[p][r] * 0.25f;
                float fi = acci[p][r] * 0.25f;
                float mag2 = fmaf(fr, fr, fmaf(fi, fi, 1e-8f));
                float rmag = __builtin_amdgcn_rsqf(mag2);       // 1/mag
                float magv = mag2 * rmag;                       // mag
                float e = __builtin_amdgcn_exp2f(g2[r] * magv); // exp(-2*g*mag)
                float th = 1.0f - 2.0f * e * __builtin_amdgcn_rcpf(1.0f + e);
                float scv = th * rmag;                          // tanh/mag
                pr[r] = (__bf16)(fr * scv); pi[r] = (__bf16)(fi * scv);
            }
            const int off = ((j0 >> 3) * 128 + n) * 8 + (j0 & 7);
            *(bf16x4*)(OBr + off) = pr;
            *(bf16x4*)(OBi + off) = pi;
        }
    };

    __syncthreads();                                // CrL/CiL staged

    // register-cache A-frags for k-chunks quad (kt=0) and 4+quad (kt=1):
    // conn is time-invariant, these 12 frags (48 VGPR) feed every step.
    bf16x8 cR0[3], cI0[3], cR1[3], cI1[3];
    {
        const int a0 = (quad * MT + 48 * mg + ln15) * 8;
        const int a1 = ((4 + quad) * MT + 48 * mg + ln15) * 8;
#pragma unroll
        for (int mt = 0; mt < 3; ++mt) {
            cR0[mt] = *(const bf16x8*)(CrL + a0 + 128 * mt);
            cI0[mt] = *(const bf16x8*)(CiL + a0 + 128 * mt);
            cR1[mt] = *(const bf16x8*)(CrL + a1 + 128 * mt);
            cI1[mt] = *(const bf16x8*)(CiL + a1 + 128 * mt);
        }
    }

    inj_add();                                      // t = 0 (out is zero)
    epilogue();
    __syncthreads();

    for (int t = 1; t < NSTEPS - 1; ++t) {
#pragma unroll
        for (int p = 0; p < 6; ++p) { accr[p] *= 0.85f; acci[p] *= 0.85f; }
        if (t < INJ_ST) inj_add();

        // ---- kt = 0,1: A from registers, B from LDS (8 ds_reads total) ----
#pragma unroll
        for (int pn = 0; pn < 2; ++pn) {
            const int nb = ((2 * ng + pn) * 16 + ln15) * 8;
            bf16x8 br0 = *(const bf16x8*)(OBr + quad * 1024 + nb);
            bf16x8 bi0 = *(const bf16x8*)(OBi + quad * 1024 + nb);
            bf16x8 bn0 = bneg(bi0);
            CMUL3(cR0[0], cI0[0], cR0[1], cI0[1], cR0[2], cI0[2], br0, bi0, bn0, pn)
            bf16x8 br1 = *(const bf16x8*)(OBr + (4 + quad) * 1024 + nb);
            bf16x8 bi1 = *(const bf16x8*)(OBi + (4 + quad) * 1024 + nb);
            bf16x8 bn1 = bneg(bi1);
            CMUL3(cR1[0], cI1[0], cR1[1], cI1[1], cR1[2], cI1[2], br1, bi1, bn1, pn)
        }

        // ---- kt = 2..4: LDS path. Skipped at t=1: out(0) rows >=49 are
        // exactly zero (injection only), so chunks >=8 contribute nothing.
        // kch 18,19 remap to chunk 17 (zeros). unroll(1): R12-R14 lesson.
        if (t > 1) {
#pragma unroll 1
            for (int kt = 2; kt < 5; ++kt) {
                const int kch = kt * 4 + quad;
                const int rk  = (kch > 17) ? 17 : kch;
                const int abase = (rk * MT + 48 * mg + ln15) * 8;
                bf16x8 ar0 = *(const bf16x8*)(CrL + abase);
                bf16x8 ar1 = *(const bf16x8*)(CrL + abase + 128);
                bf16x8 ar2 = *(const bf16x8*)(CrL + abase + 256);
                bf16x8 ai0 = *(const bf16x8*)(CiL + abase);
                bf16x8 ai1 = *(const bf16x8*)(CiL + abase + 128);
                bf16x8 ai2 = *(const bf16x8*)(CiL + abase + 256);
#pragma unroll
                for (int pn = 0; pn < 2; ++pn) {
                    const int boff = (rk * 128 + (2 * ng + pn) * 16 + ln15) * 8;
                    bf16x8 b_r = *(const bf16x8*)(OBr + boff);
                    bf16x8 b_i = *(const bf16x8*)(OBi + boff);
                    bf16x8 b_n = bneg(b_i);
                    CMUL3(ar0, ai0, ar1, ai1, ar2, ai2, b_r, b_i, b_n, pn)
                }
            }
        }
        __syncthreads();   // all reads of OB done
        epilogue();
        __syncthreads();   // OB ready
    }

    // ---- t = 9: only rows 121..130 feed the energy -> mg2 waves only,
    // tiles 7,8 only, no OB writeback. Bit-identical math for kept rows. ----
    if (mg == 2) {
#pragma unroll
        for (int p = 2; p < 6; ++p) { accr[p] *= 0.85f; acci[p] *= 0.85f; }
#pragma unroll
        for (int pn = 0; pn < 2; ++pn) {
            const int nb = ((2 * ng + pn) * 16 + ln15) * 8;
            bf16x8 br0 = *(const bf16x8*)(OBr + quad * 1024 + nb);
            bf16x8 bi0 = *(const bf16x8*)(OBi + quad * 1024 + nb);
            bf16x8 bn0 = bneg(bi0);
            CMUL2(cR0[1], cI0[1], cR0[2], cI0[2], br0, bi0, bn0, pn)
            bf16x8 br1 = *(const bf16x8*)(OBr + (4 + quad) * 1024 + nb);
            bf16x8 bi1 = *(const bf16x8*)(OBi + (4 + quad) * 1024 + nb);
            bf16x8 bn1 = bneg(bi1);
            CMUL2(cR1[1], cI1[1], cR1[2], cI1[2], br1, bi1, bn1, pn)
        }
#pragma unroll 1
        for (int kt = 2; kt < 5; ++kt) {
            const int kch = kt * 4 + quad;
            const int rk  = (kch > 17) ? 17 : kch;
            const int abase = (rk * MT + 96 + ln15) * 8;   // mg=2 rows
            bf16x8 ar1 = *(const bf16x8*)(CrL + abase + 128);
            bf16x8 ar2 = *(const bf16x8*)(CrL + abase + 256);
            bf16x8 ai1 = *(const bf16x8*)(CiL + abase + 128);
            bf16x8 ai2 = *(const bf16x8*)(CiL + abase + 256);
#pragma unroll
            for (int pn = 0; pn < 2; ++pn) {
                const int boff = (rk * 128 + (2 * ng + pn) * 16 + ln15) * 8;
                bf16x8 b_r = *(const bf16x8*)(OBr + boff);
                bf16x8 b_i = *(const bf16x8*)(OBi + boff);
                bf16x8 b_n = bneg(b_i);
                CMUL2(ar1, ai1, ar2, ai2, b_r, b_i, b_n, pn)
            }
        }
        // epilogue for energy rows: fp32 |out|^2 -> scrE (aliases CrL ch0-1,
        // which is only read via the register cache after block start).
#pragma unroll
        for (int p = 2; p < 6; ++p) {
            const int j0 = (6 + (p >> 1)) * 16 + quad * 4;
            const int n  = (2 * ng + (p & 1)) * 16 + ln15;
            float g2[4];
            *(float4*)g2 = *(const float4*)(gsp2 + j0);
#pragma unroll
            for (int r = 0; r < 4; ++r) {
                int j = j0 + r;
                if (j >= 121 && j <= 130) {
                    float fr = accr[p][r] * 0.25f;
                    float fi = acci[p][r] * 0.25f;
                    float mag2 = fmaf(fr, fr, fmaf(fi, fi, 1e-8f));
                    float rmag = __builtin_amdgcn_rsqf(mag2);
                    float magv = mag2 * rmag;
                    float e = __builtin_amdgcn_exp2f(g2[r] * magv);
                    float th = 1.0f - 2.0f * e * __builtin_amdgcn_rcpf(1.0f + e);
                    float scv = th * rmag;
                    float orv = fr * scv, oiv = fi * scv;
                    scrE[(j - 121) * 128 + n] = orv * orv + oiv * oiv;
                }
            }
        }
    }
    __syncthreads();   // scrE complete

    // ---- energy: scrE[10][128] holds exact fp32 |out|^2 ----
    if (tid < 10) {
        float ssum = 0.f;
        for (int cc = 0; cc < 128; ++cc) ssum += scrE[tid * 128 + cc];
        atomicAdd(energy + b * 10 + tid, ssum);
    }
}

__global__ void k_readout(const float* __restrict__ ws,
                          const float* __restrict__ W,
                          const float* __restrict__ bias,
                          float* __restrict__ out) {
    int i = blockIdx.x * 256 + threadIdx.x;
    if (i < 1280) {
        int b = i / 10, o = i % 10;
        float s = bias[o];
#pragma unroll
        for (int f = 0; f < 10; ++f) {
            float feat = log1pf(ws[WS_ENERGY + b * 10 + f] + 1e-8f);
            s = fmaf(feat, W[o * 10 + f], s);
        }
        out[i] = s;
    }
}

extern "C" void kernel_launch(void* const* d_in, const int* in_sizes, int n_in,
                              void* d_out, int out_size, void* d_ws, size_t ws_size,
                              hipStream_t stream) {
    const float* images = (const float*)d_in[0];
    const float* conn_r = (const float*)d_in[1];
    const float* conn_i = (const float*)d_in[2];
    const float* phase  = (const float*)d_in[3];
    const float* gain   = (const float*)d_in[4];
    const float* W      = (const float*)d_in[5];
    const float* bias   = (const float*)d_in[6];
    float* ws  = (float*)d_ws;
    float* out = (float*)d_out;

    hipLaunchKernelGGL(k_init, dim3(6), dim3(256), 0, stream, ws);
    hipLaunchKernelGGL(k_max, dim3(98), dim3(256), 0, stream, images, ws, 128 * 28 * 28);
    hipLaunchKernelGGL(k_prep, dim3(484), dim3(256), 0, stream,
                       images, conn_r, conn_i, phase, gain, ws);
    hipLaunchKernelGGL(k_main, dim3(1024), dim3(768), 0, stream, ws, ws + WS_ENERGY);
    hipLaunchKernelGGL(k_readout, dim3(5), dim3(256), 0, stream, ws, W, bias, out);
}